// Round 3
// baseline (15509.152 us; speedup 1.0000x reference)
//
#include <hip/hip_runtime.h>
#include <math.h>

#define T_LEN 512
#define BATCH 128
#define HID   256
#define BH    (BATCH*HID)   // 32768

// ---------------- helpers ----------------
// fast reciprocal: v_rcp_f32 + 1 Newton step (~0.5 ulp, way cheaper than exact div)
__device__ __forceinline__ float frcp(float d) {
    float r = __builtin_amdgcn_rcpf(d);
    return r * fmaf(-d, r, 2.0f);
}
__device__ __forceinline__ float sigmoid_f(float v) {
    return frcp(1.f + __expf(-v));
}
__device__ __forceinline__ float tanh_f(float v) {
    v = fminf(fmaxf(v, -15.f), 15.f);
    const float e = __expf(2.f * v);
    return (e - 1.f) * frcp(e + 1.f);
}
__device__ __forceinline__ float4 ldf4(const float* p) {
    return *reinterpret_cast<const float4*>(p);
}
__device__ __forceinline__ void fma4(float4& a, const float4 v, const float4 w) {
    a.x = fmaf(v.x, w.x, a.x);
    a.y = fmaf(v.y, w.y, a.y);
    a.z = fmaf(v.z, w.z, a.z);
    a.w = fmaf(v.w, w.w, a.w);
}
__device__ __forceinline__ float hsum4(const float4 a) {
    return (a.x + a.y) + (a.z + a.w);
}
// Pin a value into a VGPR so invariant weight loads can't be sunk into the loop.
// (Round-2 lesson: AGPR forcing adds accvgpr_read copies at use sites — don't.)
__device__ __forceinline__ void pin4(float4& v) {
    asm volatile("" : "+v"(v.x), "+v"(v.y), "+v"(v.z), "+v"(v.w));
}
// agent-scope relaxed atomics: coherent across XCDs, no cache flushes
__device__ __forceinline__ void astore(float* p, float v) {
    __hip_atomic_store(p, v, __ATOMIC_RELAXED, __HIP_MEMORY_SCOPE_AGENT);
}
__device__ __forceinline__ float2 af2(const float* p) {
    unsigned long long u = __hip_atomic_load((const unsigned long long*)p,
                                             __ATOMIC_RELAXED, __HIP_MEMORY_SCOPE_AGENT);
    union { unsigned long long u; float2 f; } c; c.u = u;
    return c.f;
}
__device__ __forceinline__ float4 af4(const float* p) {
    const float2 a = af2(p), b = af2(p + 2);
    return make_float4(a.x, a.y, b.x, b.y);
}
// DPP row_shr prefix reduction within 16-lane groups; lane (kc==15) gets the sum.
template<int CTRL>
__device__ __forceinline__ float dpp_mv(float x) {
    return __int_as_float(__builtin_amdgcn_update_dpp(
        0, __float_as_int(x), CTRL, 0xF, 0xF, true));
}
__device__ __forceinline__ float red16(float x) {
    x += dpp_mv<0x111>(x);  // row_shr:1
    x += dpp_mv<0x112>(x);  // row_shr:2
    x += dpp_mv<0x114>(x);  // row_shr:4
    x += dpp_mv<0x118>(x);  // row_shr:8
    return x;               // valid in lane kc==15 of each 16-group
}

// ---------------- persistent LSTM, wave-granular pipeline ----------------
// grid 512 x 256, 2 blocks/CU, IDENTITY decode (bg = bid&15 keeps each
// 32-block bg-group on one XCD under round-robin dispatch — round-2 showed
// breaking this costs 6.7x FETCH and big latency).
//
// Wave-granular sync (the change this round):
//  - flags are per (bg, layer, jt, WAVE): 128 per bg-group. A wave publishes
//    its own 4 j-columns right after ITS crit GEMV + vmcnt(0) — no waiting
//    for sibling waves' epilogues.
//  - ONE __syncthreads per step (staging -> compute). ls_in double-buffered
//    by s&1; safety: a wave staging buf[s&1] at iter s+2 passed poll(s+2),
//    which requires own-block waves to have published s+2 = finished iter
//    s+1 crit, so all readers of buf[s&1] (iters s, s+1 use alternating
//    buffers) are done.
//  - poll: lane l waits fbase[l] >= s (64 L0 wave-flags) and
//    fbase[64+l] >= thr1 (64 L1 wave-flags); thr1 = s-1 for L0 consumers
//    (buffer-reuse gate only), s for L1.
// Schedule per layer unchanged from round 1 (verified): L0 computes h0[s-1]
// at iter s, L1 computes h1[s-3]; input-half partials carried in registers.
//
// LDS layout (new): col c of combined K=512 -> row c>>4 (32 rows), offset
// c&15, row stride 20 floats (80 B: 16B-aligned b128, banks collide at most
// 2-way which is free). Per b: 640 floats. Double-buffered: 2*8*640 floats.
__global__ __launch_bounds__(256)
__attribute__((amdgpu_waves_per_eu(2, 2)))
void lstm_persist(
    const float* __restrict__ x,
    const float* __restrict__ Wih, const float* __restrict__ Whh,
    const float* __restrict__ bih, const float* __restrict__ bhh,
    float* __restrict__ out,
    float* __restrict__ h0buf,   // 3 * BH (triple-buffered by timestep%3)
    float* __restrict__ h1buf,   // 3 * BH
    int* __restrict__ flags)     // 16 bg-groups x 128 wave-flags
{
    __shared__ float ls_in[2 * 8 * 640];   // 40 KiB, double-buffered

    const int tid = threadIdx.x;
    const int bid = blockIdx.x;
    const int bg = bid & 15;
    const int layer = (bid >> 4) & 1;
    const int jt = bid >> 5;
    const int w = tid >> 6;
    const int lane = tid & 63;
    const int jp = tid >> 4;
    const int kc = tid & 15;
    const int j = jt * 16 + jp;
    const int Bg0 = bg * 8;

    const float* Wih_l = Wih + (size_t)layer * 4 * HID * HID;
    const float* Whh_l = Whh + (size_t)layer * 4 * HID * HID;
    const float* bih_l = bih + layer * 4 * HID;
    const float* bhh_l = bhh + layer * 4 * HID;

    // Weights: 4 gates x 16 K-cols per half = 128 floats, pinned VGPRs.
    float4 wih[4][4], whh[4][4];
    float bias[4];
    #pragma unroll
    for (int g = 0; g < 4; ++g) {
        const int row = g * HID + j;             // row in 4H
        const float* pih = Wih_l + (size_t)row * HID + kc * 16;
        const float* phh = Whh_l + (size_t)row * HID + kc * 16;
        #pragma unroll
        for (int m = 0; m < 4; ++m) {
            wih[g][m] = ldf4(pih + m * 4);
            pin4(wih[g][m]);
            whh[g][m] = ldf4(phh + m * 4);
            pin4(whh[g][m]);
        }
        bias[g] = bih_l[row] + bhh_l[row];
        asm volatile("" : "+v"(bias[g]));
    }

    // per-owner cell state (valid in kc==15 lanes) and carried input-half
    // per-lane partial sums (all lanes; reduced jointly with crit next iter).
    float c_reg[8];
    float ax[8][4];
    #pragma unroll
    for (int b = 0; b < 8; ++b) {
        c_reg[b] = 0.f;
        #pragma unroll
        for (int g = 0; g < 4; ++g) ax[b][g] = 0.f;
    }

    int* fbase = flags + bg * 128;
    int* myflag = fbase + layer * 64 + jt * 4 + w;

    #pragma unroll 1
    for (int s = 0; s <= T_LEN + 2; ++s) {
        if (s > 0) {
            // per-wave poll: 64 L0 wave-flags (>= s) + 64 L1 wave-flags.
            // signed compare: 0xAAAAAAAA poison is negative -> blocks until real store
            const int thr1 = (layer == 0) ? (s - 1) : s;
            const int* f0 = fbase + lane;
            const int* f1 = fbase + 64 + lane;
            while (__hip_atomic_load(f0, __ATOMIC_RELAXED, __HIP_MEMORY_SCOPE_AGENT) < s)
                __builtin_amdgcn_s_sleep(1);
            while (__hip_atomic_load(f1, __ATOMIC_RELAXED, __HIP_MEMORY_SCOPE_AGENT) < thr1)
                __builtin_amdgcn_s_sleep(1);
        }

        // crit: compute h[t] (t = s-1 for L0, s-3 for L1) from recurrent half.
        // xact: input-half partial sums for the step after t (per-lane, regs).
        const bool crit = (layer == 0) ? (s >= 1 && s <= T_LEN) : (s >= 3);
        const bool xact = (layer == 0) ? (s < T_LEN) : (s >= 2 && s <= T_LEN + 1);
        const bool zeroh = (layer == 0) ? (s == 1) : (s == 3);   // h[t-1] = 0

        float* ls = ls_in + (s & 1) * 5120;

        if (crit || xact) {
            // cols 0..255 = input half | 256..511 = recurrent half
            const float* ph0 = h0buf + (size_t)((s + 1) % 3) * BH;  // h0[s-2]
            const float* ph1 = h1buf + (size_t)((s + 2) % 3) * BH;  // h1[s-4]
            #pragma unroll
            for (int i = 0; i < 4; ++i) {
                const int F = tid + 256 * i;     // f4 index in 8 b x 128
                const int b = F >> 7;
                const int rr = F & 127;          // global col = rr*4
                const size_t row = (size_t)(Bg0 + b) * HID + (rr & 63) * 4;
                float4 v = make_float4(0.f, 0.f, 0.f, 0.f);
                if ((rr >> 6) == 0) {            // input half (slack)
                    if (xact)
                        v = (layer == 0) ? ldf4(x + (size_t)s * BH + row)
                                         : af4(ph0 + row);
                } else if (crit && !zeroh) {     // recurrent half (critical)
                    v = (layer == 0) ? af4(ph0 + row) : af4(ph1 + row);
                }
                // col 4rr -> row rr>>2, off (rr&3)*4; stride 20
                *(float4*)(ls + b * 640 + (rr >> 2) * 20 + (rr & 3) * 4) = v;
            }
        }
        __syncthreads();   // the ONLY barrier: staging visible to all waves

        if (crit) {
            const int t = (layer == 0) ? (s - 1) : (s - 3);
            float* hst = (layer == 0) ? (h0buf + (size_t)((s + 2) % 3) * BH)  // h0[s-1]
                                      : (h1buf + (size_t)(s % 3) * BH);       // h1[s-3]
            const bool last = (t == T_LEN - 1);
            // ---- CRITICAL: recurrent K=256 GEMV + joint reduce + owner epilogue
            // lane kc chunk: cols 256+16kc..+15 -> row 16+kc
            #pragma unroll 2
            for (int b = 0; b < 8; ++b) {
                const float4* Lp = (const float4*)(ls + b * 640 + (16 + kc) * 20);
                float4 i0 = Lp[0], i1 = Lp[1], i2 = Lp[2], i3 = Lp[3];
                float4 ac[4];
                #pragma unroll
                for (int g = 0; g < 4; ++g) ac[g] = make_float4(0.f, 0.f, 0.f, 0.f);
                #pragma unroll
                for (int g = 0; g < 4; ++g) {
                    fma4(ac[g], i0, whh[g][0]);
                    fma4(ac[g], i1, whh[g][1]);
                    fma4(ac[g], i2, whh[g][2]);
                    fma4(ac[g], i3, whh[g][3]);
                }
                // add carried input-half partial BEFORE the cross-lane reduce
                const float r0 = red16(hsum4(ac[0]) + ax[b][0]);
                const float r1 = red16(hsum4(ac[1]) + ax[b][1]);
                const float r2 = red16(hsum4(ac[2]) + ax[b][2]);
                const float r3 = red16(hsum4(ac[3]) + ax[b][3]);
                if (kc == 15) {   // owner lane: full epilogue, c in registers
                    const float gi = sigmoid_f(r0 + bias[0]);
                    const float gf = sigmoid_f(r1 + bias[1]);
                    const float gg = tanh_f   (r2 + bias[2]);
                    const float go = sigmoid_f(r3 + bias[3]);
                    const float cnew = fmaf(gf, c_reg[b], gi * gg);
                    c_reg[b] = cnew;
                    const float h = go * tanh_f(cnew);
                    const int B = Bg0 + b;
                    astore(hst + (size_t)B * HID + j, h);
                    if (layer == 1)
                        out[(size_t)t * BH + (size_t)B * HID + j] = h;
                    if (last) {
                        float* hn  = out + (size_t)T_LEN * BH;
                        float* cnp = hn + 2 * BH;
                        hn [(size_t)layer * BH + (size_t)B * HID + j] = h;
                        cnp[(size_t)layer * BH + (size_t)B * HID + j] = cnew;
                    }
                }
            }
        }
        // drain THIS wave's h-stores, then publish THIS wave's flag — no
        // waiting on sibling waves.
        asm volatile("s_waitcnt vmcnt(0)" ::: "memory");
        if (s <= T_LEN + 1 && lane == 0)
            __hip_atomic_store(myflag, s + 1, __ATOMIC_RELAXED, __HIP_MEMORY_SCOPE_AGENT);

        if (xact) {
            // ---- SLACK: input-half K=256 GEMV for the NEXT step, after the
            // flag is already out. Per-lane partials only; no reduce, no LDS.
            // lane kc chunk: cols 16kc..+15 -> row kc
            #pragma unroll 2
            for (int b = 0; b < 8; ++b) {
                const float4* Lp = (const float4*)(ls + b * 640 + kc * 20);
                float4 i0 = Lp[0], i1 = Lp[1], i2 = Lp[2], i3 = Lp[3];
                float4 ac[4];
                #pragma unroll
                for (int g = 0; g < 4; ++g) ac[g] = make_float4(0.f, 0.f, 0.f, 0.f);
                #pragma unroll
                for (int g = 0; g < 4; ++g) {
                    fma4(ac[g], i0, wih[g][0]);
                    fma4(ac[g], i1, wih[g][1]);
                    fma4(ac[g], i2, wih[g][2]);
                    fma4(ac[g], i3, wih[g][3]);
                }
                #pragma unroll
                for (int g = 0; g < 4; ++g) ax[b][g] = hsum4(ac[g]);
            }
        }
    }
}

extern "C" void kernel_launch(void* const* d_in, const int* in_sizes, int n_in,
                              void* d_out, int out_size, void* d_ws, size_t ws_size,
                              hipStream_t stream) {
    const float* x   = (const float*)d_in[0];
    const float* Wih = (const float*)d_in[1];
    const float* Whh = (const float*)d_in[2];
    const float* bih = (const float*)d_in[3];
    const float* bhh = (const float*)d_in[4];
    float* out = (float*)d_out;

    float* h0 = (float*)d_ws;          // 3*BH
    float* h1 = h0 + 3 * BH;           // 3*BH
    int* flags = (int*)(h1 + 3 * BH);  // 2048 ints, poison-proof (signed compare)

    hipLaunchKernelGGL(lstm_persist, dim3(512), dim3(256), 0, stream,
                       x, Wih, Whh, bih, bhh, out, h0, h1, flags);
}

// Round 4
// 4569.039 us; speedup vs baseline: 3.3944x; 3.3944x over previous
//
#include <hip/hip_runtime.h>
#include <math.h>

#define T_LEN 512
#define BATCH 128
#define HID   256
#define BH    (BATCH*HID)   // 32768

typedef float v2f __attribute__((ext_vector_type(2)));

// ---------------- helpers ----------------
// fast reciprocal: v_rcp_f32 + 1 Newton step (~0.5 ulp, cheaper than exact div)
__device__ __forceinline__ float frcp(float d) {
    float r = __builtin_amdgcn_rcpf(d);
    return r * fmaf(-d, r, 2.0f);
}
__device__ __forceinline__ float sigmoid_f(float v) {
    return frcp(1.f + __expf(-v));
}
__device__ __forceinline__ float tanh_f(float v) {
    v = fminf(fmaxf(v, -15.f), 15.f);
    const float e = __expf(2.f * v);
    return (e - 1.f) * frcp(e + 1.f);
}
__device__ __forceinline__ float4 ldf4(const float* p) {
    return *reinterpret_cast<const float4*>(p);
}
// packed fp32 FMA: 2 MACs per instruction (VOP3P, gfx90a+). Halves the
// issue-slot cost of the GEMV inner loops (we are issue-bound, not FLOP-bound).
__device__ __forceinline__ v2f pkfma(v2f a, v2f b, v2f c) {
    v2f d;
    asm("v_pk_fma_f32 %0, %1, %2, %3" : "=v"(d) : "v"(a), "v"(b), "v"(c));
    return d;
}
__device__ __forceinline__ v2f lo2(const float4 v) { v2f r; r.x = v.x; r.y = v.y; return r; }
__device__ __forceinline__ v2f hi2(const float4 v) { v2f r; r.x = v.z; r.y = v.w; return r; }
// Pin weights into registers (asm def can't be rematerialized into the loop).
// (Round-2 lesson: do NOT force AGPRs explicitly — accvgpr_read copies at uses.)
__device__ __forceinline__ void pin2(v2f& v) {
    asm volatile("" : "+v"(v));
}
// agent-scope relaxed atomics: coherent across XCDs, no cache flushes
__device__ __forceinline__ void astore(float* p, float v) {
    __hip_atomic_store(p, v, __ATOMIC_RELAXED, __HIP_MEMORY_SCOPE_AGENT);
}
__device__ __forceinline__ float2 af2(const float* p) {
    unsigned long long u = __hip_atomic_load((const unsigned long long*)p,
                                             __ATOMIC_RELAXED, __HIP_MEMORY_SCOPE_AGENT);
    union { unsigned long long u; float2 f; } c; c.u = u;
    return c.f;
}
__device__ __forceinline__ float4 af4(const float* p) {
    const float2 a = af2(p), b = af2(p + 2);
    return make_float4(a.x, a.y, b.x, b.y);
}
// DPP row_shr prefix reduction within 16-lane groups; lane (kc==15) gets the sum.
template<int CTRL>
__device__ __forceinline__ float dpp_mv(float x) {
    return __int_as_float(__builtin_amdgcn_update_dpp(
        0, __float_as_int(x), CTRL, 0xF, 0xF, true));
}
__device__ __forceinline__ float red16(float x) {
    x += dpp_mv<0x111>(x);  // row_shr:1
    x += dpp_mv<0x112>(x);  // row_shr:2
    x += dpp_mv<0x114>(x);  // row_shr:4
    x += dpp_mv<0x118>(x);  // row_shr:8
    return x;               // valid in lane kc==15 of each 16-group
}

// ---------------- persistent LSTM ----------------
// grid 512 x 256, 2 blocks/CU, IDENTITY decode (bg = bid&15 keeps each
// 32-block bg-group on one XCD; round 2 proved breaking this costs 6.7x FETCH).
// Sync skeleton = round 1 (proven): block-granular flags (32/bg-group),
// 32 poller lanes. Round 3 proved widening the poll army to all lanes causes
// a coherence-fabric congestion collapse (FETCH 119 MB -> 12 GB) — never again.
//
// Schedule: L0 computes h0[s-1] at iter s (lag 1); L1 computes h1[s-3] (lag 3).
// Per iter: poll -> B1 -> stage [x|h] into ls[s&1] -> B2 -> critical K=256
// recurrent GEMV (pk_fma) + carried input-half partials + owner-lane epilogue
// -> per-wave vmcnt(0) + LDS arrive-counter; LAST wave publishes block flag
// (replaces the 3rd barrier) -> input-half K=256 GEMV for the next step into
// per-lane ax[] registers (slack work inside the publish->poll window).
//
// LDS: col c of combined K=512 -> row c>>4 (32 rows) offset c&15, row stride
// 20 floats (16B-aligned b128; measured 8x fewer bank conflicts than the
// round-1 layout). Double-buffered by s&1.
__global__ __launch_bounds__(256)
__attribute__((amdgpu_waves_per_eu(2, 2)))
void lstm_persist(
    const float* __restrict__ x,
    const float* __restrict__ Wih, const float* __restrict__ Whh,
    const float* __restrict__ bih, const float* __restrict__ bhh,
    float* __restrict__ out,
    float* __restrict__ h0buf,   // 3 * BH (triple-buffered by timestep%3)
    float* __restrict__ h1buf,   // 3 * BH
    int* __restrict__ flags)     // 16 bg-groups x 32 block flags
{
    __shared__ float ls_in[2 * 8 * 640];   // 40 KiB, double-buffered
    __shared__ int arrive;                  // monotonic, 4 per iteration

    const int tid = threadIdx.x;
    const int bid = blockIdx.x;
    const int bg = bid & 15;
    const int layer = (bid >> 4) & 1;
    const int jt = bid >> 5;
    const int jp = tid >> 4;
    const int kc = tid & 15;
    const int j = jt * 16 + jp;
    const int Bg0 = bg * 8;

    const float* Wih_l = Wih + (size_t)layer * 4 * HID * HID;
    const float* Whh_l = Whh + (size_t)layer * 4 * HID * HID;
    const float* bih_l = bih + layer * 4 * HID;
    const float* bhh_l = bhh + layer * 4 * HID;

    // Weights: 4 gates x 16 K-cols per half = 128 floats, as v2f pairs for
    // v_pk_fma_f32, pinned.
    v2f wih2[4][8], whh2[4][8];
    float bias[4];
    #pragma unroll
    for (int g = 0; g < 4; ++g) {
        const int row = g * HID + j;             // row in 4H
        const float* pih = Wih_l + (size_t)row * HID + kc * 16;
        const float* phh = Whh_l + (size_t)row * HID + kc * 16;
        #pragma unroll
        for (int m = 0; m < 4; ++m) {
            const float4 a = ldf4(pih + m * 4);
            wih2[g][2 * m]     = lo2(a); pin2(wih2[g][2 * m]);
            wih2[g][2 * m + 1] = hi2(a); pin2(wih2[g][2 * m + 1]);
            const float4 b = ldf4(phh + m * 4);
            whh2[g][2 * m]     = lo2(b); pin2(whh2[g][2 * m]);
            whh2[g][2 * m + 1] = hi2(b); pin2(whh2[g][2 * m + 1]);
        }
        bias[g] = bih_l[row] + bhh_l[row];
        asm volatile("" : "+v"(bias[g]));
    }

    // per-owner cell state (kc==15 lanes) and carried input-half partials.
    float c_reg[8];
    float ax[8][4];
    #pragma unroll
    for (int b = 0; b < 8; ++b) {
        c_reg[b] = 0.f;
        #pragma unroll
        for (int g = 0; g < 4; ++g) ax[b][g] = 0.f;
    }

    if (tid == 0) arrive = 0;   // visible after first __syncthreads

    int* myflag = flags + bg * 32 + layer * 16 + jt;

    #pragma unroll 1
    for (int s = 0; s <= T_LEN + 2; ++s) {
        if (s > 0 && tid < 32) {
            // signed compare: 0xAAAAAAAA poison is negative -> blocks until real store
            const int thr = (layer == 0 && tid >= 16) ? (s - 1) : s;
            const int* f = flags + bg * 32 + tid;
            while (__hip_atomic_load(f, __ATOMIC_RELAXED, __HIP_MEMORY_SCOPE_AGENT) < thr)
                __builtin_amdgcn_s_sleep(1);
        }
        __syncthreads();   // B1: inputs published & visible

        // crit: compute h[t] (t = s-1 for L0, s-3 for L1) from recurrent half.
        // xact: input-half partial sums for the step after t (per-lane, regs).
        const bool crit = (layer == 0) ? (s >= 1 && s <= T_LEN) : (s >= 3);
        const bool xact = (layer == 0) ? (s < T_LEN) : (s >= 2 && s <= T_LEN + 1);
        const bool zeroh = (layer == 0) ? (s == 1) : (s == 3);   // h[t-1] = 0

        float* ls = ls_in + (s & 1) * 5120;

        if (crit || xact) {
            // cols 0..255 = input half | 256..511 = recurrent half
            const float* ph0 = h0buf + (size_t)((s + 1) % 3) * BH;  // h0[s-2]
            const float* ph1 = h1buf + (size_t)((s + 2) % 3) * BH;  // h1[s-4]
            #pragma unroll
            for (int i = 0; i < 4; ++i) {
                const int F = tid + 256 * i;     // f4 index in 8 b x 128
                const int b = F >> 7;
                const int rr = F & 127;          // global col = rr*4
                const size_t row = (size_t)(Bg0 + b) * HID + (rr & 63) * 4;
                float4 v = make_float4(0.f, 0.f, 0.f, 0.f);
                if ((rr >> 6) == 0) {            // input half (slack)
                    if (xact)
                        v = (layer == 0) ? ldf4(x + (size_t)s * BH + row)
                                         : af4(ph0 + row);
                } else if (crit && !zeroh) {     // recurrent half (critical)
                    v = (layer == 0) ? af4(ph0 + row) : af4(ph1 + row);
                }
                // col 4rr -> row rr>>2, float-off (rr&3)*4; row stride 20
                *(float4*)(ls + b * 640 + (rr >> 2) * 20 + (rr & 3) * 4) = v;
            }
        }
        __syncthreads();   // B2: staging visible to all waves

        if (crit) {
            const int t = (layer == 0) ? (s - 1) : (s - 3);
            float* hst = (layer == 0) ? (h0buf + (size_t)((s + 2) % 3) * BH)  // h0[s-1]
                                      : (h1buf + (size_t)(s % 3) * BH);       // h1[s-3]
            const bool last = (t == T_LEN - 1);
            // ---- CRITICAL: recurrent K=256 GEMV (pk_fma) + reduce + owner epilogue
            // lane kc chunk: cols 256+16kc..+15 -> row 16+kc
            #pragma unroll 2
            for (int b = 0; b < 8; ++b) {
                const float4* Lp = (const float4*)(ls + b * 640 + (16 + kc) * 20);
                const float4 i0 = Lp[0], i1 = Lp[1], i2 = Lp[2], i3 = Lp[3];
                v2f ac[4];
                #pragma unroll
                for (int g = 0; g < 4; ++g) { ac[g].x = 0.f; ac[g].y = 0.f; }
                #pragma unroll
                for (int g = 0; g < 4; ++g) {
                    ac[g] = pkfma(lo2(i0), whh2[g][0], ac[g]);
                    ac[g] = pkfma(hi2(i0), whh2[g][1], ac[g]);
                    ac[g] = pkfma(lo2(i1), whh2[g][2], ac[g]);
                    ac[g] = pkfma(hi2(i1), whh2[g][3], ac[g]);
                    ac[g] = pkfma(lo2(i2), whh2[g][4], ac[g]);
                    ac[g] = pkfma(hi2(i2), whh2[g][5], ac[g]);
                    ac[g] = pkfma(lo2(i3), whh2[g][6], ac[g]);
                    ac[g] = pkfma(hi2(i3), whh2[g][7], ac[g]);
                }
                // add carried input-half partial BEFORE the cross-lane reduce
                const float r0 = red16(ac[0].x + ac[0].y + ax[b][0]);
                const float r1 = red16(ac[1].x + ac[1].y + ax[b][1]);
                const float r2 = red16(ac[2].x + ac[2].y + ax[b][2]);
                const float r3 = red16(ac[3].x + ac[3].y + ax[b][3]);
                if (kc == 15) {   // owner lane: full epilogue, c in registers
                    const float gi = sigmoid_f(r0 + bias[0]);
                    const float gf = sigmoid_f(r1 + bias[1]);
                    const float gg = tanh_f   (r2 + bias[2]);
                    const float go = sigmoid_f(r3 + bias[3]);
                    const float cnew = fmaf(gf, c_reg[b], gi * gg);
                    c_reg[b] = cnew;
                    const float h = go * tanh_f(cnew);
                    const int B = Bg0 + b;
                    astore(hst + (size_t)B * HID + j, h);
                    if (layer == 1)
                        out[(size_t)t * BH + (size_t)B * HID + j] = h;
                    if (last) {
                        float* hn  = out + (size_t)T_LEN * BH;
                        float* cnp = hn + 2 * BH;
                        hn [(size_t)layer * BH + (size_t)B * HID + j] = h;
                        cnp[(size_t)layer * BH + (size_t)B * HID + j] = cnew;
                    }
                }
            }
        }
        // ---- arrive counter replaces the pre-publish barrier: each wave drains
        // its OWN h-stores, increments; the 4th arriver publishes the block flag.
        asm volatile("s_waitcnt vmcnt(0)" ::: "memory");
        if ((tid & 63) == 0) {
            const int old = __hip_atomic_fetch_add(&arrive, 1, __ATOMIC_RELAXED,
                                                   __HIP_MEMORY_SCOPE_WORKGROUP);
            if (old == 4 * s + 3 && s <= T_LEN + 1)
                __hip_atomic_store(myflag, s + 1, __ATOMIC_RELAXED,
                                   __HIP_MEMORY_SCOPE_AGENT);
        }

        if (xact) {
            // ---- SLACK: input-half K=256 GEMV for the NEXT step, after the
            // flag path. Per-lane partials only; no reduce, no LDS writes.
            // lane kc chunk: cols 16kc..+15 -> row kc
            #pragma unroll 2
            for (int b = 0; b < 8; ++b) {
                const float4* Lp = (const float4*)(ls + b * 640 + kc * 20);
                const float4 i0 = Lp[0], i1 = Lp[1], i2 = Lp[2], i3 = Lp[3];
                v2f ac[4];
                #pragma unroll
                for (int g = 0; g < 4; ++g) { ac[g].x = 0.f; ac[g].y = 0.f; }
                #pragma unroll
                for (int g = 0; g < 4; ++g) {
                    ac[g] = pkfma(lo2(i0), wih2[g][0], ac[g]);
                    ac[g] = pkfma(hi2(i0), wih2[g][1], ac[g]);
                    ac[g] = pkfma(lo2(i1), wih2[g][2], ac[g]);
                    ac[g] = pkfma(hi2(i1), wih2[g][3], ac[g]);
                    ac[g] = pkfma(lo2(i2), wih2[g][4], ac[g]);
                    ac[g] = pkfma(hi2(i2), wih2[g][5], ac[g]);
                    ac[g] = pkfma(lo2(i3), wih2[g][6], ac[g]);
                    ac[g] = pkfma(hi2(i3), wih2[g][7], ac[g]);
                }
                #pragma unroll
                for (int g = 0; g < 4; ++g) ax[b][g] = ac[g].x + ac[g].y;
            }
        }
    }
}

extern "C" void kernel_launch(void* const* d_in, const int* in_sizes, int n_in,
                              void* d_out, int out_size, void* d_ws, size_t ws_size,
                              hipStream_t stream) {
    const float* x   = (const float*)d_in[0];
    const float* Wih = (const float*)d_in[1];
    const float* Whh = (const float*)d_in[2];
    const float* bih = (const float*)d_in[3];
    const float* bhh = (const float*)d_in[4];
    float* out = (float*)d_out;

    float* h0 = (float*)d_ws;          // 3*BH
    float* h1 = h0 + 3 * BH;           // 3*BH
    int* flags = (int*)(h1 + 3 * BH);  // 512 ints, poison-proof (signed compare)

    hipLaunchKernelGGL(lstm_persist, dim3(512), dim3(256), 0, stream,
                       x, Wih, Whh, bih, bhh, out, h0, h1, flags);
}